// Round 10
// baseline (745.264 us; speedup 1.0000x reference)
//
#include <hip/hip_runtime.h>
#include <stdint.h>

typedef unsigned short u16;
typedef __bf16 bf16x8 __attribute__((ext_vector_type(8)));
typedef float f32x4 __attribute__((ext_vector_type(4)));
typedef float f32x16 __attribute__((ext_vector_type(16)));

#define DEV static __device__ __forceinline__

// f32 -> bf16 round-to-nearest-even (finite inputs only)
DEV u16 f2bf(float f) {
  uint32_t u = __float_as_uint(f);
  u += 0x7fffu + ((u >> 16) & 1u);
  return (u16)(u >> 16);
}

// async global->LDS, 16B per lane; lds dest is wave-uniform base (HW adds lane*16)
DEV void g2l16(const void* g, void* l) {
  __builtin_amdgcn_global_load_lds(
      (__attribute__((address_space(1))) void*)(g),
      (__attribute__((address_space(3))) void*)(l), 16, 0, 0);
}

DEV f32x4 mfma16(bf16x8 a, bf16x8 b, f32x4 c) {
  return __builtin_amdgcn_mfma_f32_16x16x32_bf16(a, b, c, 0, 0, 0);
}
DEV f32x16 mfma32(bf16x8 a, bf16x8 b, f32x16 c) {
  return __builtin_amdgcn_mfma_f32_32x32x16_bf16(a, b, c, 0, 0, 0);
}

DEV bf16x8 lds_ld(const char* p) { return *(const bf16x8*)p; }

// single-instruction 2^x (avoids any OCML exp2 codepath)
DEV float fexp2(float x) {
  float r;
  asm("v_exp_f32 %0, %1" : "=v"(r) : "v"(x));
  return r;
}

// pack two f32 to one u32 of 2 bf16 (lo from src0)
DEV uint32_t cvtpk(float lo, float hi) {
  uint32_t r;
  asm("v_cvt_pk_bf16_f32 %0, %1, %2" : "=v"(r) : "v"(lo), "v"(hi));
  return r;
}
// swap: a.hi-lanes <-> b.lo-lanes (T12 redistribution primitive)
DEV void pswap(uint32_t& a, uint32_t& b) {
  auto r = __builtin_amdgcn_permlane32_swap((int)a, (int)b, false, false);
  a = (uint32_t)r[0];
  b = (uint32_t)r[1];
}
DEV float xhalf_sum(float x) {
  auto r = __builtin_amdgcn_permlane32_swap(__float_as_int(x), __float_as_int(x), false, false);
  return __int_as_float(r[0]) + __int_as_float(r[1]);
}

// ---------------- f32 -> bf16 cast, 4 elems/thread ----------------
__global__ __launch_bounds__(256) void cvt_kernel(const float* __restrict__ in,
                                                  u16* __restrict__ out, int n4) {
  int i = blockIdx.x * 256 + threadIdx.x;
  if (i >= n4) return;
  float4 v = ((const float4*)in)[i];
  ushort4 o;
  o.x = f2bf(v.x); o.y = f2bf(v.y); o.z = f2bf(v.z); o.w = f2bf(v.w);
  ((ushort4*)out)[i] = o;
}

// ---------------- C[M,N] = A[M,K] * B[N,K]^T + bias (R8 known-good) ----------------
// EPI=1 (qkv gemm): cols < qcols scaled by qscale (softmax scale folded into Q);
//   tiles with bn0 >= vcol0 are the V slice, written TRANSPOSED into vT.
// EPI=0: plain f32 C output.
template<int EPI>
__global__ __launch_bounds__(256, 2) void gemm_bt(
    const u16* __restrict__ A, const u16* __restrict__ B,
    const float* __restrict__ bias, void* __restrict__ C,
    u16* __restrict__ vT,
    int M, int N, int K, int qcols, float qscale, int vcol0) {
  __shared__ char sm[2][32768];
  const int tid = threadIdx.x;
  const int w = tid >> 6, l = tid & 63;
  const int wr = w >> 1, wc = w & 1;
  const int bm0 = blockIdx.x * 128, bn0 = blockIdx.y * 128;
  const int lr = l >> 3, lsl = (l & 7) ^ lr;
  const u16* gA = A + (size_t)(bm0 + w * 32 + lr) * K + lsl * 8;
  const u16* gB = B + (size_t)(bn0 + w * 32 + lr) * K + lsl * 8;

  auto stage = [&](int t, int pp) {
    char* ba = sm[pp] + w * 32 * 128;
    char* bb = ba + 16384;
    const u16* a = gA + t * 64;
    const u16* b = gB + t * 64;
#pragma unroll
    for (int i = 0; i < 4; ++i) {
      g2l16(a + (size_t)i * 8 * K, ba + i * 8 * 128);
      g2l16(b + (size_t)i * 8 * K, bb + i * 8 * 128);
    }
  };

  f32x4 acc[4][4] = {};
  const int NT = K / 64;
  int pp = 0;
  stage(0, 0);
  __syncthreads();
  for (int t = 0; t < NT; ++t) {
    if (t + 1 < NT) stage(t + 1, pp ^ 1);
    const char* bufA = sm[pp];
    const char* bufB = bufA + 16384;
#pragma unroll
    for (int ks = 0; ks < 2; ++ks) {
      bf16x8 af[4], bfr[4];
#pragma unroll
      for (int i = 0; i < 4; ++i) {
        const int rowA = wr * 64 + i * 16 + (l & 15);
        const int colb = (ks * 64 + ((l >> 4) << 4)) ^ ((rowA & 7) << 4);
        af[i] = lds_ld(bufA + rowA * 128 + colb);
        const int rowB = wc * 64 + i * 16 + (l & 15);
        bfr[i] = lds_ld(bufB + rowB * 128 + colb);
      }
#pragma unroll
      for (int i = 0; i < 4; ++i)
#pragma unroll
        for (int j = 0; j < 4; ++j)
          acc[i][j] = mfma16(af[i], bfr[j], acc[i][j]);
    }
    __syncthreads();
    pp ^= 1;
  }
  const int cr = (l >> 4) * 4, cc = l & 15;
  if (EPI == 1 && bn0 >= vcol0) {
#pragma unroll
    for (int i = 0; i < 4; ++i) {
      const int gr = bm0 + wr * 64 + i * 16 + cr;
      const int b = gr >> 11, s = gr & 2047;
#pragma unroll
      for (int j = 0; j < 4; ++j) {
        const int gc = bn0 + wc * 64 + j * 16 + cc;
        const float bv = bias[gc];
        const int vc = gc - vcol0;
        u16* dst = vT + ((size_t)((b * 16 + (vc >> 6)) * 64 + (vc & 63))) * 2048 + s;
        ushort4 pk;
        pk.x = f2bf(acc[i][j][0] + bv);
        pk.y = f2bf(acc[i][j][1] + bv);
        pk.z = f2bf(acc[i][j][2] + bv);
        pk.w = f2bf(acc[i][j][3] + bv);
        *(ushort4*)dst = pk;
      }
    }
    return;
  }
#pragma unroll
  for (int i = 0; i < 4; ++i) {
    const int gr = bm0 + wr * 64 + i * 16 + cr;
#pragma unroll
    for (int j = 0; j < 4; ++j) {
      const int gc = bn0 + wc * 64 + j * 16 + cc;
      const float bv = bias[gc];
      const float scl = (gc < qcols) ? qscale : 1.0f;
#pragma unroll
      for (int r = 0; r < 4; ++r) {
        const float v = (acc[i][j][r] + bv) * scl;
        if (EPI == 0) ((float*)C)[(size_t)(gr + r) * N + gc] = v;
        else          ((u16*)C)[(size_t)(gr + r) * N + gc] = f2bf(v);
      }
    }
  }
}

// ---------------- flash attention: kv-split 8-wave blocks ----------------
// 1-D grid 512, 512 thr = 2 kv-groups x 4 q-waves. Group g handles kv tiles
// [16g,16g+16) for the SAME 256 q-rows; each group owns a 32KB double-buffer.
// 2 blocks/CU x 8 waves = 4 waves/SIMD (vs 2 before): fills the ~60% latency
// idle measured at R7. Fixed-max softmax makes the cross-group combine a PURE
// SUM (no rescale): group 1 dumps unnormalized O + partial lsum to the retired
// staging LDS, one barrier, group 0 adds + normalizes + writes.
// XCD-chunked bh mapping keeps K/V L2-resident (R7, -74% FETCH).
__global__ __launch_bounds__(512, 4) void attn(const u16* __restrict__ qkv,
                                               const u16* __restrict__ vT,
                                               u16* __restrict__ ctx) {
  constexpr int S = 2048, E = 1024, TE = 3072, NTH = 16;  // tiles per kv-half
  const int id = blockIdx.x;
  const int x = id & 7, j = id >> 3;
  const int bh = x * 8 + (j & 7), qt = j >> 3;
  const int b = bh >> 4, h = bh & 15;
  const int tid = threadIdx.x, w = tid >> 6, l = tid & 63;
  const int g = w >> 2, wi = w & 3;  // kv-group, q-wave within group
  const int q = l & 31, hi = l >> 5;
  __shared__ char sm[67584];  // 2 groups x 2 bufs x 16KB staging + 2KB aux
  char* const gbase = sm + g * 32768;
  float* const combO = (float*)sm;           // reused post-loop (64KB)
  float* const aux = (float*)(sm + 65536);   // lsum partials [wi][qb][lane]

  // Q fragments: SAME q rows for both kv-groups
  const int qglobA = qt * 256 + wi * 64 + q;
  const int qglobB = qglobA + 32;
  const u16* qpA = qkv + (size_t)(b * S + qglobA) * TE + h * 64 + hi * 8;
  const u16* qpB = qkv + (size_t)(b * S + qglobB) * TE + h * 64 + hi * 8;
  bf16x8 qfA[4], qfB[4];
#pragma unroll
  for (int d = 0; d < 4; ++d) {
    qfA[d] = *(const bf16x8*)(qpA + d * 16);
    qfB[d] = *(const bf16x8*)(qpB + d * 16);
  }

  const int lr = l >> 3, lsl = (l & 7) ^ lr;  // pre-swizzled source slot (rule 21)
  const u16* gK = qkv + (size_t)(b * S) * TE + E + h * 64 + lsl * 8;
  const u16* gV = vT + (size_t)(bh * 64) * S + lsl * 8;

  auto stage = [&](int t, int pp) {  // t = local tile within this group's half
    char* bk = gbase + pp * 16384 + wi * 2048;
    const int tt = g * NTH + t;
#pragma unroll
    for (int i = 0; i < 2; ++i) {
      const int row = wi * 16 + i * 8 + lr;
      g2l16(gK + (size_t)(tt * 64 + row) * TE, bk + i * 1024);      // K rows (kv)
      g2l16(gV + (size_t)row * S + tt * 64, bk + 8192 + i * 1024);  // V^T rows (d)
    }
  };

  f32x16 o0A = {}, o1A = {}, o0B = {}, o1B = {};
  float lsumA = 0.f, lsumB = 0.f;

  auto expsum = [&](f32x16& e, float& ls) {
    float ts[4] = {0.f, 0.f, 0.f, 0.f};
#pragma unroll
    for (int r = 0; r < 16; ++r) {
      e[r] = fexp2(e[r]);
      ts[r & 3] += e[r];
    }
    ls += (ts[0] + ts[1]) + (ts[2] + ts[3]);
  };
  auto mkfrag = [&](const f32x16& e, bf16x8& P0, bf16x8& P1) {
    uint32_t a0 = cvtpk(e[0], e[1]), c0 = cvtpk(e[4], e[5]);
    uint32_t a1 = cvtpk(e[2], e[3]), c1 = cvtpk(e[6], e[7]);
    pswap(a0, c0); pswap(a1, c1);
    uint32_t a2 = cvtpk(e[8], e[9]), c2 = cvtpk(e[12], e[13]);
    uint32_t a3 = cvtpk(e[10], e[11]), c3 = cvtpk(e[14], e[15]);
    pswap(a2, c2); pswap(a3, c3);
    union { uint32_t u[4]; bf16x8 v; } t0, t1;
    t0.u[0] = a0; t0.u[1] = a1; t0.u[2] = c0; t0.u[3] = c1;
    t1.u[0] = a2; t1.u[1] = a3; t1.u[2] = c2; t1.u[3] = c3;
    P0 = t0.v; P1 = t1.v;
  };

  int pp = 0;
  stage(0, 0);
  __syncthreads();
  for (int t = 0; t < NTH; ++t) {
    if (t + 1 < NTH) stage(t + 1, pp ^ 1);
    const char* bK = gbase + pp * 16384;
    const char* bV = bK + 8192;
    const int swz = (q & 7) << 4;
#pragma unroll
    for (int s = 0; s < 2; ++s) {  // 32-kv sub-pass
      const char* kr = bK + (s * 32 + q) * 128;
      bf16x8 kf[4];
#pragma unroll
      for (int d = 0; d < 4; ++d) kf[d] = lds_ld(kr + (((d * 2 + hi) << 4) ^ swz));
      f32x16 stA = {}, stB = {};
      __builtin_amdgcn_s_setprio(1);
#pragma unroll
      for (int d = 0; d < 4; ++d) {  // interleaved A/B chains: 2x MFMA ILP
        stA = mfma32(kf[d], qfA[d], stA);
        stB = mfma32(kf[d], qfB[d], stB);
      }
      __builtin_amdgcn_s_setprio(0);
      const int s0 = (((s * 4 + hi) << 4) ^ swz);
      const int s1 = (((s * 4 + 2 + hi) << 4) ^ swz);
      const bf16x8 va0 = lds_ld(bV + q * 128 + s0);
      const bf16x8 va1 = lds_ld(bV + q * 128 + s1);
      const bf16x8 vb0 = lds_ld(bV + (32 + q) * 128 + s0);
      const bf16x8 vb1 = lds_ld(bV + (32 + q) * 128 + s1);
      expsum(stA, lsumA);
      expsum(stB, lsumB);
      bf16x8 pA0, pA1, pB0, pB1;
      mkfrag(stA, pA0, pA1);
      mkfrag(stB, pB0, pB1);
      __builtin_amdgcn_s_setprio(1);
      o0A = mfma32(va0, pA0, o0A); o0B = mfma32(va0, pB0, o0B);
      o0A = mfma32(va1, pA1, o0A); o0B = mfma32(va1, pB1, o0B);
      o1A = mfma32(vb0, pA0, o1A); o1B = mfma32(vb0, pB0, o1B);
      o1A = mfma32(vb1, pA1, o1A); o1B = mfma32(vb1, pB1, o1B);
      __builtin_amdgcn_s_setprio(0);
    }
    __syncthreads();  // also seals the last tile's staging reads
    pp ^= 1;
  }
  // ---- cross-group combine (pure sum: fixed-max softmax, no rescale) ----
  if (g == 1) {
    // layout [wi][r][lane]: conflict-free (stride 4B across lanes)
    float* dst = combO + (size_t)(wi * 64) * 64 + l;
#pragma unroll
    for (int r = 0; r < 16; ++r) {
      dst[(r) * 64]      = o0A[r];
      dst[(16 + r) * 64] = o1A[r];
      dst[(32 + r) * 64] = o0B[r];
      dst[(48 + r) * 64] = o1B[r];
    }
    aux[(wi * 2 + 0) * 64 + l] = lsumA;
    aux[(wi * 2 + 1) * 64 + l] = lsumB;
  }
  __syncthreads();
  if (g == 0) {
    const float* src = combO + (size_t)(wi * 64) * 64 + l;
#pragma unroll
    for (int r = 0; r < 16; ++r) {
      o0A[r] += src[(r) * 64];
      o1A[r] += src[(16 + r) * 64];
      o0B[r] += src[(32 + r) * 64];
      o1B[r] += src[(48 + r) * 64];
    }
    lsumA += aux[(wi * 2 + 0) * 64 + l];
    lsumB += aux[(wi * 2 + 1) * 64 + l];
    // epilogue: O^T reg r -> d = db*32 + (r&3) + 8*(r>>2) + 4*hi, row = qglob
    auto writeo = [&](const f32x16& e0, const f32x16& e1, float ls, int qg) {
      const float inv = 1.0f / xhalf_sum(ls);
      u16* cp = ctx + (size_t)(b * S + qg) * E + h * 64 + 4 * hi;
#pragma unroll
      for (int gg = 0; gg < 4; ++gg) {
        ushort4 pk0, pk1;
        pk0.x = f2bf(e0[4 * gg + 0] * inv); pk0.y = f2bf(e0[4 * gg + 1] * inv);
        pk0.z = f2bf(e0[4 * gg + 2] * inv); pk0.w = f2bf(e0[4 * gg + 3] * inv);
        *(ushort4*)(cp + 8 * gg) = pk0;
        pk1.x = f2bf(e1[4 * gg + 0] * inv); pk1.y = f2bf(e1[4 * gg + 1] * inv);
        pk1.z = f2bf(e1[4 * gg + 2] * inv); pk1.w = f2bf(e1[4 * gg + 3] * inv);
        *(ushort4*)(cp + 32 + 8 * gg) = pk1;
      }
    };
    writeo(o0A, o1A, lsumA, qglobA);
    writeo(o0B, o1B, lsumB, qglobB);
  }
}

extern "C" void kernel_launch(void* const* d_in, const int* in_sizes, int n_in,
                              void* d_out, int out_size, void* d_ws, size_t ws_size,
                              hipStream_t stream) {
  (void)in_sizes; (void)n_in; (void)out_size;
  const float* inp   = (const float*)d_in[0];
  const float* qkv_w = (const float*)d_in[1];
  const float* qkv_b = (const float*)d_in[2];
  const float* out_w = (const float*)d_in[3];
  const float* out_b = (const float*)d_in[4];
  char* ws = (char*)d_ws;
  if (ws_size < 92274688u) return;  // need ~88 MB scratch

  u16* inp_b  = (u16*)(ws);                  // 16,777,216 B  (reused as ctx later)
  u16* qkvw_b = (u16*)(ws + 16777216);       //  6,291,456 B
  u16* outw_b = (u16*)(ws + 23068672);       //  2,097,152 B
  u16* qkvo   = (u16*)(ws + 25165824);       // 50,331,648 B  [8192, 3072] bf16 (V cols unused)
  u16* vTb    = (u16*)(ws + 75497472);       // 16,777,216 B  [B*H*64, 2048] bf16
  u16* ctx    = inp_b;

  const float cexp = 0.18033688f;  // log2(e)/sqrt(64), folded into Q columns

  hipLaunchKernelGGL(cvt_kernel, dim3(8192), dim3(256), 0, stream, inp, inp_b, 2097152);
  hipLaunchKernelGGL(cvt_kernel, dim3(3072), dim3(256), 0, stream, qkv_w, qkvw_b, 786432);
  hipLaunchKernelGGL(cvt_kernel, dim3(1024), dim3(256), 0, stream, out_w, outw_b, 262144);
  hipLaunchKernelGGL((gemm_bt<1>), dim3(64, 24), dim3(256), 0, stream,
                     inp_b, qkvw_b, qkv_b, (void*)qkvo, vTb,
                     8192, 3072, 1024, 1024, cexp, 2048);
  hipLaunchKernelGGL(attn, dim3(512), dim3(512), 0, stream, qkvo, vTb, ctx);
  hipLaunchKernelGGL((gemm_bt<0>), dim3(64, 8), dim3(256), 0, stream,
                     ctx, outw_b, out_b, d_out, (u16*)nullptr,
                     8192, 1024, 1024, 0, 1.0f, 1 << 30);
}

// Round 11
// 177.360 us; speedup vs baseline: 4.2020x; 4.2020x over previous
//
#include <hip/hip_runtime.h>
#include <stdint.h>

typedef unsigned short u16;
typedef __bf16 bf16x8 __attribute__((ext_vector_type(8)));
typedef float f32x4 __attribute__((ext_vector_type(4)));
typedef float f32x16 __attribute__((ext_vector_type(16)));

#define DEV static __device__ __forceinline__

// f32 -> bf16 round-to-nearest-even (finite inputs only)
DEV u16 f2bf(float f) {
  uint32_t u = __float_as_uint(f);
  u += 0x7fffu + ((u >> 16) & 1u);
  return (u16)(u >> 16);
}

// async global->LDS, 16B per lane; lds dest is wave-uniform base (HW adds lane*16)
DEV void g2l16(const void* g, void* l) {
  __builtin_amdgcn_global_load_lds(
      (__attribute__((address_space(1))) void*)(g),
      (__attribute__((address_space(3))) void*)(l), 16, 0, 0);
}

DEV f32x4 mfma16(bf16x8 a, bf16x8 b, f32x4 c) {
  return __builtin_amdgcn_mfma_f32_16x16x32_bf16(a, b, c, 0, 0, 0);
}
DEV f32x16 mfma32(bf16x8 a, bf16x8 b, f32x16 c) {
  return __builtin_amdgcn_mfma_f32_32x32x16_bf16(a, b, c, 0, 0, 0);
}

DEV bf16x8 lds_ld(const char* p) { return *(const bf16x8*)p; }

DEV float fexp2(float x) {
  float r;
  asm("v_exp_f32 %0, %1" : "=v"(r) : "v"(x));
  return r;
}
DEV uint32_t cvtpk(float lo, float hi) {
  uint32_t r;
  asm("v_cvt_pk_bf16_f32 %0, %1, %2" : "=v"(r) : "v"(lo), "v"(hi));
  return r;
}
DEV void pswap(uint32_t& a, uint32_t& b) {
  auto r = __builtin_amdgcn_permlane32_swap((int)a, (int)b, false, false);
  a = (uint32_t)r[0];
  b = (uint32_t)r[1];
}
DEV float xhalf_sum(float x) {
  auto r = __builtin_amdgcn_permlane32_swap(__float_as_int(x), __float_as_int(x), false, false);
  return __int_as_float(r[0]) + __int_as_float(r[1]);
}
// steady-state counted wait (T4); -1 = none
DEV void vwait(int n) {
  if (n == 2) asm volatile("s_waitcnt vmcnt(2)" ::: "memory");
  else if (n == 0) asm volatile("s_waitcnt vmcnt(0)" ::: "memory");
}

// ---------------- f32 -> bf16 cast, 4 elems/thread ----------------
__global__ __launch_bounds__(256) void cvt_kernel(const float* __restrict__ in,
                                                  u16* __restrict__ out, int n4) {
  int i = blockIdx.x * 256 + threadIdx.x;
  if (i >= n4) return;
  float4 v = ((const float4*)in)[i];
  ushort4 o;
  o.x = f2bf(v.x); o.y = f2bf(v.y); o.z = f2bf(v.z); o.w = f2bf(v.w);
  ((ushort4*)out)[i] = o;
}

// -------- C[M,N] = A[M,K] * B[N,K]^T + bias: 2-phase counted-vmcnt schedule --------
// BM=256 BN=128 BK=64, 512 thr = 8 waves (2M x 4N), wave-tile 128x32, acc[8][2].
// LDS 96KB: A dbuf 2x32KB @0, B dbuf 2x16KB @65536, XOR-swizzled rows.
// K-tile = 2 phases: ph0 reads A-half0 + all B (reg-held), 16 MFMA; ph1 reads
// A-half1, 16 MFMA. Stage units = 64-row quarters (1 g2l16/wave). Schedule
// (iter u computes tiles 2u in buf0 [P1,P2] and 2u+1 in buf1 [P3,P4]):
//   P1 stages: A-q1,q3 + B-h0 of tile 2u+1 (regions dead since P4/P3 prev iter)
//   P2 stages: B-h1(2u+1), A-q0,q2(2u+2)  (A-mh0 of 2u died at P1)
//   P3 stages: A-q1,q3 + B-h0 of 2u+2      (A-mh1 died P2; B died P1, reg-held)
//   P4 stages: B-h1(2u+2), A-q0,q2(2u+3)   (tile 2u+1's A-mh0 died P3)
// Waits: vmcnt(2) BEFORE the barrier at end of P2 (gates P3/P4 reading tile
// 2u+1; 2 youngest = A-q0,q2 of 2u+2 stay in flight) and at end of P4 (gates
// next P1/P2). Wait-then-barrier collects ALL waves' loads. Never vmcnt(0)
// in steady state; tail iters degrade to 0 via guards.
template<int EPI>
__global__ __launch_bounds__(512, 2) void gemm256(
    const u16* __restrict__ A, const u16* __restrict__ B,
    const float* __restrict__ bias, void* __restrict__ C,
    u16* __restrict__ vT,
    int M, int N, int K, int qcols, float qscale, int vcol0) {
  __shared__ char sm[98304];
  const int tid = threadIdx.x;
  const int w = tid >> 6, l = tid & 63;
  const int wm = w >> 2, wn = w & 3;
  const int bm0 = blockIdx.x * 256, bn0 = blockIdx.y * 128;
  const int lr = l >> 3, lsl = (l & 7) ^ lr;  // pre-swizzled source slot (rule 21)
  const u16* gA = A + (size_t)(bm0 + w * 8 + lr) * K + lsl * 8;
  const u16* gB = B + (size_t)(bn0 + w * 8 + lr) * K + lsl * 8;
  const int NT = K / 64, NU = NT / 2;
  const int la = l & 15, hs = l >> 4;

  auto stA = [&](int t, int qa) {  // one 64-row A quarter, 1 g2l16/wave
    g2l16(gA + ((size_t)(qa * 64) * K + t * 64),
          sm + (t & 1) * 32768 + (qa * 64 + w * 8) * 128);
  };
  auto stB = [&](int t, int hb) {  // one 64-row B half, 1 g2l16/wave
    g2l16(gB + ((size_t)(hb * 64) * K + t * 64),
          sm + 65536 + (t & 1) * 16384 + (hb * 64 + w * 8) * 128);
  };

  f32x4 acc[8][2] = {};

  auto tileC = [&](int buf, auto&& s1, auto&& s2, int ev1, int ev2) {
    const char* bA = sm + buf * 32768;
    const char* bB = sm + 65536 + buf * 16384;
    bf16x8 af[4][2], bfr[2][2];
    // ---- phase 0 (A rows wm*128+0..63) ----
#pragma unroll
    for (int m = 0; m < 4; ++m) {
      const int row = wm * 128 + m * 16 + la;
      const int sw = (row & 7) << 4;
#pragma unroll
      for (int ks = 0; ks < 2; ++ks)
        af[m][ks] = lds_ld(bA + row * 128 + (((ks * 4 + hs) << 4) ^ sw));
    }
#pragma unroll
    for (int nf = 0; nf < 2; ++nf) {
      const int row = wn * 32 + nf * 16 + la;
      const int sw = (row & 7) << 4;
#pragma unroll
      for (int ks = 0; ks < 2; ++ks)
        bfr[nf][ks] = lds_ld(bB + row * 128 + (((ks * 4 + hs) << 4) ^ sw));
    }
    s1();
    __builtin_amdgcn_s_barrier();
    asm volatile("s_waitcnt lgkmcnt(0)" ::: "memory");
    __builtin_amdgcn_sched_barrier(0);
    __builtin_amdgcn_s_setprio(1);
#pragma unroll
    for (int m = 0; m < 4; ++m)
#pragma unroll
      for (int nf = 0; nf < 2; ++nf)
#pragma unroll
        for (int ks = 0; ks < 2; ++ks)
          acc[m][nf] = mfma16(af[m][ks], bfr[nf][ks], acc[m][nf]);
    __builtin_amdgcn_s_setprio(0);
    vwait(ev1);
    __builtin_amdgcn_s_barrier();
    __builtin_amdgcn_sched_barrier(0);
    // ---- phase 1 (A rows wm*128+64..127; B reg-held) ----
#pragma unroll
    for (int m = 0; m < 4; ++m) {
      const int row = wm * 128 + 64 + m * 16 + la;
      const int sw = (row & 7) << 4;
#pragma unroll
      for (int ks = 0; ks < 2; ++ks)
        af[m][ks] = lds_ld(bA + row * 128 + (((ks * 4 + hs) << 4) ^ sw));
    }
    s2();
    __builtin_amdgcn_s_barrier();
    asm volatile("s_waitcnt lgkmcnt(0)" ::: "memory");
    __builtin_amdgcn_sched_barrier(0);
    __builtin_amdgcn_s_setprio(1);
#pragma unroll
    for (int m = 0; m < 4; ++m)
#pragma unroll
      for (int nf = 0; nf < 2; ++nf)
#pragma unroll
        for (int ks = 0; ks < 2; ++ks)
          acc[4 + m][nf] = mfma16(af[m][ks], bfr[nf][ks], acc[4 + m][nf]);
    __builtin_amdgcn_s_setprio(0);
    vwait(ev2);
    __builtin_amdgcn_s_barrier();
    __builtin_amdgcn_sched_barrier(0);
  };

  // prologue: tile0 fully, tile1's A-q0,q2 (mirrors steady-state P4 slot)
  stA(0, 0); stA(0, 1); stA(0, 2); stA(0, 3); stB(0, 0); stB(0, 1);
  stA(1, 0); stA(1, 2);
  asm volatile("s_waitcnt vmcnt(2)" ::: "memory");
  __builtin_amdgcn_s_barrier();
  __builtin_amdgcn_sched_barrier(0);

  for (int u = 0; u < NU; ++u) {
    const int t1 = 2 * u + 1, t2 = 2 * u + 2, t3 = 2 * u + 3;
    tileC(0,
          [&] { stA(t1, 1); stA(t1, 3); stB(t1, 0); },
          [&] { stB(t1, 1); if (t2 < NT) { stA(t2, 0); stA(t2, 2); } },
          -1, (t2 < NT) ? 2 : 0);
    tileC(1,
          [&] { if (t2 < NT) { stA(t2, 1); stA(t2, 3); stB(t2, 0); } },
          [&] { if (t2 < NT) stB(t2, 1); if (t3 < NT) { stA(t3, 0); stA(t3, 2); } },
          -1, (t3 < NT) ? 2 : ((t2 < NT) ? 0 : -1));
  }

  // epilogue: C/D col=l&15, row=(l>>4)*4+r; mf -> row offset (mf>>2)*64+(mf&3)*16
  const int cr = hs * 4, cc = la;
  if (EPI == 1 && bn0 >= vcol0) {
    // V-slice tile: transposed store straight from accumulator
#pragma unroll
    for (int mf = 0; mf < 8; ++mf) {
      const int gr = bm0 + wm * 128 + (mf >> 2) * 64 + (mf & 3) * 16 + cr;
      const int b = gr >> 11, s = gr & 2047;
#pragma unroll
      for (int nf = 0; nf < 2; ++nf) {
        const int gc = bn0 + wn * 32 + nf * 16 + cc;
        const float bv = bias[gc];
        const int vc = gc - vcol0;
        u16* dst = vT + ((size_t)((b * 16 + (vc >> 6)) * 64 + (vc & 63))) * 2048 + s;
        ushort4 pk;
        pk.x = f2bf(acc[mf][nf][0] + bv);
        pk.y = f2bf(acc[mf][nf][1] + bv);
        pk.z = f2bf(acc[mf][nf][2] + bv);
        pk.w = f2bf(acc[mf][nf][3] + bv);
        *(ushort4*)dst = pk;
      }
    }
    return;
  }
#pragma unroll
  for (int mf = 0; mf < 8; ++mf) {
    const int gr = bm0 + wm * 128 + (mf >> 2) * 64 + (mf & 3) * 16 + cr;
#pragma unroll
    for (int nf = 0; nf < 2; ++nf) {
      const int gc = bn0 + wn * 32 + nf * 16 + cc;
      const float bv = bias[gc];
      const float scl = (gc < qcols) ? qscale : 1.0f;
#pragma unroll
      for (int r = 0; r < 4; ++r) {
        const float v = (acc[mf][nf][r] + bv) * scl;
        if (EPI == 0) ((float*)C)[(size_t)(gr + r) * N + gc] = v;
        else          ((u16*)C)[(size_t)(gr + r) * N + gc] = f2bf(v);
      }
    }
  }
}

// ---------------- flash attention (R8 known-good, reverted) ----------------
__global__ __launch_bounds__(256, 2) void attn(const u16* __restrict__ qkv,
                                               const u16* __restrict__ vT,
                                               u16* __restrict__ ctx) {
  constexpr int S = 2048, E = 1024, TE = 3072, NT = S / 64;
  const int id = blockIdx.x;
  const int x = id & 7, j = id >> 3;
  const int bh = x * 8 + (j & 7), qt = j >> 3;
  const int b = bh >> 4, h = bh & 15;
  const int tid = threadIdx.x, w = tid >> 6, l = tid & 63;
  const int q = l & 31, hi = l >> 5;
  __shared__ char sm[2][16384];

  const int qglobA = qt * 256 + w * 64 + q;
  const int qglobB = qglobA + 32;
  const u16* qpA = qkv + (size_t)(b * S + qglobA) * TE + h * 64 + hi * 8;
  const u16* qpB = qkv + (size_t)(b * S + qglobB) * TE + h * 64 + hi * 8;
  bf16x8 qfA[4], qfB[4];
#pragma unroll
  for (int d = 0; d < 4; ++d) {
    qfA[d] = *(const bf16x8*)(qpA + d * 16);
    qfB[d] = *(const bf16x8*)(qpB + d * 16);
  }

  const int lr = l >> 3, lsl = (l & 7) ^ lr;
  const u16* gK = qkv + (size_t)(b * S) * TE + E + h * 64 + lsl * 8;
  const u16* gV = vT + (size_t)(bh * 64) * S + lsl * 8;

  auto stage = [&](int t, int pp) {
    char* bk = sm[pp] + w * 2048;
#pragma unroll
    for (int i = 0; i < 2; ++i) {
      const int row = w * 16 + i * 8 + lr;
      g2l16(gK + (size_t)(t * 64 + row) * TE, bk + i * 1024);
      g2l16(gV + (size_t)row * S + t * 64, bk + 8192 + i * 1024);
    }
  };

  f32x16 o0A = {}, o1A = {}, o0B = {}, o1B = {};
  float lsumA = 0.f, lsumB = 0.f;

  auto expsum = [&](f32x16& e, float& ls) {
    float ts[4] = {0.f, 0.f, 0.f, 0.f};
#pragma unroll
    for (int r = 0; r < 16; ++r) {
      e[r] = fexp2(e[r]);
      ts[r & 3] += e[r];
    }
    ls += (ts[0] + ts[1]) + (ts[2] + ts[3]);
  };
  auto mkfrag = [&](const f32x16& e, bf16x8& P0, bf16x8& P1) {
    uint32_t a0 = cvtpk(e[0], e[1]), c0 = cvtpk(e[4], e[5]);
    uint32_t a1 = cvtpk(e[2], e[3]), c1 = cvtpk(e[6], e[7]);
    pswap(a0, c0); pswap(a1, c1);
    uint32_t a2 = cvtpk(e[8], e[9]), c2 = cvtpk(e[12], e[13]);
    uint32_t a3 = cvtpk(e[10], e[11]), c3 = cvtpk(e[14], e[15]);
    pswap(a2, c2); pswap(a3, c3);
    union { uint32_t u[4]; bf16x8 v; } t0, t1;
    t0.u[0] = a0; t0.u[1] = a1; t0.u[2] = c0; t0.u[3] = c1;
    t1.u[0] = a2; t1.u[1] = a3; t1.u[2] = c2; t1.u[3] = c3;
    P0 = t0.v; P1 = t1.v;
  };

  int pp = 0;
  stage(0, 0);
  __syncthreads();
  for (int t = 0; t < NT; ++t) {
    if (t + 1 < NT) stage(t + 1, pp ^ 1);
    const char* bK = sm[pp];
    const char* bV = sm[pp] + 8192;
    const int swz = (q & 7) << 4;
#pragma unroll
    for (int s = 0; s < 2; ++s) {
      const char* kr = bK + (s * 32 + q) * 128;
      bf16x8 kf[4];
#pragma unroll
      for (int d = 0; d < 4; ++d) kf[d] = lds_ld(kr + (((d * 2 + hi) << 4) ^ swz));
      f32x16 stA = {}, stB = {};
      __builtin_amdgcn_s_setprio(1);
#pragma unroll
      for (int d = 0; d < 4; ++d) {
        stA = mfma32(kf[d], qfA[d], stA);
        stB = mfma32(kf[d], qfB[d], stB);
      }
      __builtin_amdgcn_s_setprio(0);
      const int s0 = (((s * 4 + hi) << 4) ^ swz);
      const int s1 = (((s * 4 + 2 + hi) << 4) ^ swz);
      const bf16x8 va0 = lds_ld(bV + q * 128 + s0);
      const bf16x8 va1 = lds_ld(bV + q * 128 + s1);
      const bf16x8 vb0 = lds_ld(bV + (32 + q) * 128 + s0);
      const bf16x8 vb1 = lds_ld(bV + (32 + q) * 128 + s1);
      expsum(stA, lsumA);
      expsum(stB, lsumB);
      bf16x8 pA0, pA1, pB0, pB1;
      mkfrag(stA, pA0, pA1);
      mkfrag(stB, pB0, pB1);
      __builtin_amdgcn_s_setprio(1);
      o0A = mfma32(va0, pA0, o0A); o0B = mfma32(va0, pB0, o0B);
      o0A = mfma32(va1, pA1, o0A); o0B = mfma32(va1, pB1, o0B);
      o1A = mfma32(vb0, pA0, o1A); o1B = mfma32(vb0, pB0, o1B);
      o1A = mfma32(vb1, pA1, o1A); o1B = mfma32(vb1, pB1, o1B);
      __builtin_amdgcn_s_setprio(0);
    }
    __syncthreads();
    pp ^= 1;
  }
  auto writeo = [&](const f32x16& e0, const f32x16& e1, float ls, int qg) {
    const float inv = 1.0f / xhalf_sum(ls);
    u16* cp = ctx + (size_t)(b * S + qg) * E + h * 64 + 4 * hi;
#pragma unroll
    for (int g = 0; g < 4; ++g) {
      ushort4 pk0, pk1;
      pk0.x = f2bf(e0[4 * g + 0] * inv); pk0.y = f2bf(e0[4 * g + 1] * inv);
      pk0.z = f2bf(e0[4 * g + 2] * inv); pk0.w = f2bf(e0[4 * g + 3] * inv);
      *(ushort4*)(cp + 8 * g) = pk0;
      pk1.x = f2bf(e1[4 * g + 0] * inv); pk1.y = f2bf(e1[4 * g + 1] * inv);
      pk1.z = f2bf(e1[4 * g + 2] * inv); pk1.w = f2bf(e1[4 * g + 3] * inv);
      *(ushort4*)(cp + 32 + 8 * g) = pk1;
    }
  };
  writeo(o0A, o1A, lsumA, qglobA);
  writeo(o0B, o1B, lsumB, qglobB);
}

extern "C" void kernel_launch(void* const* d_in, const int* in_sizes, int n_in,
                              void* d_out, int out_size, void* d_ws, size_t ws_size,
                              hipStream_t stream) {
  (void)in_sizes; (void)n_in; (void)out_size;
  const float* inp   = (const float*)d_in[0];
  const float* qkv_w = (const float*)d_in[1];
  const float* qkv_b = (const float*)d_in[2];
  const float* out_w = (const float*)d_in[3];
  const float* out_b = (const float*)d_in[4];
  char* ws = (char*)d_ws;
  if (ws_size < 92274688u) return;  // need ~88 MB scratch

  u16* inp_b  = (u16*)(ws);                  // 16,777,216 B  (reused as ctx later)
  u16* qkvw_b = (u16*)(ws + 16777216);       //  6,291,456 B
  u16* outw_b = (u16*)(ws + 23068672);       //  2,097,152 B
  u16* qkvo   = (u16*)(ws + 25165824);       // 50,331,648 B  [8192, 3072] bf16 (V cols unused)
  u16* vTb    = (u16*)(ws + 75497472);       // 16,777,216 B  [B*H*64, 2048] bf16
  u16* ctx    = inp_b;

  const float cexp = 0.18033688f;  // log2(e)/sqrt(64), folded into Q columns

  hipLaunchKernelGGL(cvt_kernel, dim3(8192), dim3(256), 0, stream, inp, inp_b, 2097152);
  hipLaunchKernelGGL(cvt_kernel, dim3(3072), dim3(256), 0, stream, qkv_w, qkvw_b, 786432);
  hipLaunchKernelGGL(cvt_kernel, dim3(1024), dim3(256), 0, stream, out_w, outw_b, 262144);
  hipLaunchKernelGGL((gemm256<1>), dim3(32, 24), dim3(512), 0, stream,
                     inp_b, qkvw_b, qkv_b, (void*)qkvo, vTb,
                     8192, 3072, 1024, 1024, cexp, 2048);
  hipLaunchKernelGGL(attn, dim3(512), dim3(256), 0, stream, qkvo, vTb, ctx);
  hipLaunchKernelGGL((gemm256<0>), dim3(32, 8), dim3(512), 0, stream,
                     ctx, outw_b, out_b, d_out, (u16*)nullptr,
                     8192, 1024, 1024, 0, 1.0f, 1 << 30);
}

// Round 12
// 172.570 us; speedup vs baseline: 4.3186x; 1.0278x over previous
//
#include <hip/hip_runtime.h>
#include <stdint.h>

typedef unsigned short u16;
typedef __bf16 bf16x8 __attribute__((ext_vector_type(8)));
typedef float f32x4 __attribute__((ext_vector_type(4)));
typedef float f32x16 __attribute__((ext_vector_type(16)));

#define DEV static __device__ __forceinline__

// f32 -> bf16 round-to-nearest-even (finite inputs only)
DEV u16 f2bf(float f) {
  uint32_t u = __float_as_uint(f);
  u += 0x7fffu + ((u >> 16) & 1u);
  return (u16)(u >> 16);
}

// async global->LDS, 16B per lane; lds dest is wave-uniform base (HW adds lane*16)
DEV void g2l16(const void* g, void* l) {
  __builtin_amdgcn_global_load_lds(
      (__attribute__((address_space(1))) void*)(g),
      (__attribute__((address_space(3))) void*)(l), 16, 0, 0);
}

DEV f32x4 mfma16(bf16x8 a, bf16x8 b, f32x4 c) {
  return __builtin_amdgcn_mfma_f32_16x16x32_bf16(a, b, c, 0, 0, 0);
}
DEV f32x16 mfma32(bf16x8 a, bf16x8 b, f32x16 c) {
  return __builtin_amdgcn_mfma_f32_32x32x16_bf16(a, b, c, 0, 0, 0);
}

DEV bf16x8 lds_ld(const char* p) { return *(const bf16x8*)p; }

// single-instruction 2^x (avoids any OCML exp2 codepath)
DEV float fexp2(float x) {
  float r;
  asm("v_exp_f32 %0, %1" : "=v"(r) : "v"(x));
  return r;
}

// pack two f32 to one u32 of 2 bf16 (lo from src0)
DEV uint32_t cvtpk(float lo, float hi) {
  uint32_t r;
  asm("v_cvt_pk_bf16_f32 %0, %1, %2" : "=v"(r) : "v"(lo), "v"(hi));
  return r;
}
// swap: a.hi-lanes <-> b.lo-lanes (T12 redistribution primitive)
DEV void pswap(uint32_t& a, uint32_t& b) {
  auto r = __builtin_amdgcn_permlane32_swap((int)a, (int)b, false, false);
  a = (uint32_t)r[0];
  b = (uint32_t)r[1];
}
DEV float xhalf_sum(float x) {
  auto r = __builtin_amdgcn_permlane32_swap(__float_as_int(x), __float_as_int(x), false, false);
  return __int_as_float(r[0]) + __int_as_float(r[1]);
}

// ---------------- f32 -> bf16 cast, 4 elems/thread ----------------
__global__ __launch_bounds__(256) void cvt_kernel(const float* __restrict__ in,
                                                  u16* __restrict__ out, int n4) {
  int i = blockIdx.x * 256 + threadIdx.x;
  if (i >= n4) return;
  float4 v = ((const float4*)in)[i];
  ushort4 o;
  o.x = f2bf(v.x); o.y = f2bf(v.y); o.z = f2bf(v.z); o.w = f2bf(v.w);
  ((ushort4*)out)[i] = o;
}

// ---------------- C[M,N] = A[M,K] * B[N,K]^T + bias (R8 known-good) ----------------
// EPI=1 (qkv gemm): cols < qcols scaled by qscale (softmax scale folded into Q);
//   tiles with bn0 >= vcol0 are the V slice, written TRANSPOSED into vT.
// EPI=0: plain f32 C output.
template<int EPI>
__global__ __launch_bounds__(256, 2) void gemm_bt(
    const u16* __restrict__ A, const u16* __restrict__ B,
    const float* __restrict__ bias, void* __restrict__ C,
    u16* __restrict__ vT,
    int M, int N, int K, int qcols, float qscale, int vcol0) {
  __shared__ char sm[2][32768];
  const int tid = threadIdx.x;
  const int w = tid >> 6, l = tid & 63;
  const int wr = w >> 1, wc = w & 1;
  const int bm0 = blockIdx.x * 128, bn0 = blockIdx.y * 128;
  const int lr = l >> 3, lsl = (l & 7) ^ lr;
  const u16* gA = A + (size_t)(bm0 + w * 32 + lr) * K + lsl * 8;
  const u16* gB = B + (size_t)(bn0 + w * 32 + lr) * K + lsl * 8;

  auto stage = [&](int t, int pp) {
    char* ba = sm[pp] + w * 32 * 128;
    char* bb = ba + 16384;
    const u16* a = gA + t * 64;
    const u16* b = gB + t * 64;
#pragma unroll
    for (int i = 0; i < 4; ++i) {
      g2l16(a + (size_t)i * 8 * K, ba + i * 8 * 128);
      g2l16(b + (size_t)i * 8 * K, bb + i * 8 * 128);
    }
  };

  f32x4 acc[4][4] = {};
  const int NT = K / 64;
  int pp = 0;
  stage(0, 0);
  __syncthreads();
  for (int t = 0; t < NT; ++t) {
    if (t + 1 < NT) stage(t + 1, pp ^ 1);
    const char* bufA = sm[pp];
    const char* bufB = bufA + 16384;
#pragma unroll
    for (int ks = 0; ks < 2; ++ks) {
      bf16x8 af[4], bfr[4];
#pragma unroll
      for (int i = 0; i < 4; ++i) {
        const int rowA = wr * 64 + i * 16 + (l & 15);
        const int colb = (ks * 64 + ((l >> 4) << 4)) ^ ((rowA & 7) << 4);
        af[i] = lds_ld(bufA + rowA * 128 + colb);
        const int rowB = wc * 64 + i * 16 + (l & 15);
        bfr[i] = lds_ld(bufB + rowB * 128 + colb);
      }
#pragma unroll
      for (int i = 0; i < 4; ++i)
#pragma unroll
        for (int j = 0; j < 4; ++j)
          acc[i][j] = mfma16(af[i], bfr[j], acc[i][j]);
    }
    __syncthreads();
    pp ^= 1;
  }
  const int cr = (l >> 4) * 4, cc = l & 15;
  if (EPI == 1 && bn0 >= vcol0) {
#pragma unroll
    for (int i = 0; i < 4; ++i) {
      const int gr = bm0 + wr * 64 + i * 16 + cr;
      const int b = gr >> 11, s = gr & 2047;
#pragma unroll
      for (int j = 0; j < 4; ++j) {
        const int gc = bn0 + wc * 64 + j * 16 + cc;
        const float bv = bias[gc];
        const int vc = gc - vcol0;
        u16* dst = vT + ((size_t)((b * 16 + (vc >> 6)) * 64 + (vc & 63))) * 2048 + s;
        ushort4 pk;
        pk.x = f2bf(acc[i][j][0] + bv);
        pk.y = f2bf(acc[i][j][1] + bv);
        pk.z = f2bf(acc[i][j][2] + bv);
        pk.w = f2bf(acc[i][j][3] + bv);
        *(ushort4*)dst = pk;
      }
    }
    return;
  }
#pragma unroll
  for (int i = 0; i < 4; ++i) {
    const int gr = bm0 + wr * 64 + i * 16 + cr;
#pragma unroll
    for (int j = 0; j < 4; ++j) {
      const int gc = bn0 + wc * 64 + j * 16 + cc;
      const float bv = bias[gc];
      const float scl = (gc < qcols) ? qscale : 1.0f;
#pragma unroll
      for (int r = 0; r < 4; ++r) {
        const float v = (acc[i][j][r] + bv) * scl;
        if (EPI == 0) ((float*)C)[(size_t)(gr + r) * N + gc] = v;
        else          ((u16*)C)[(size_t)(gr + r) * N + gc] = f2bf(v);
      }
    }
  }
}

// ---------------- flash attention: swapped-QK^T 32x32, QBLK=32/wave ----------------
// 1-D grid 1024, 256 thr = 4 waves x 32 q-rows (128 q/block, qt 0..15).
// Combines the two proven levers: XCD-chunked bh mapping (R7: staging L2-hits,
// FETCH -74%) + 4 blocks/CU TLP (R4 structure: fills the latency idle measured
// at R7's 2 blocks/CU). Q pre-scaled by log2(e)/sqrt(D) in gemm1; fixed-max
// shift cancels in normalize -> exp is bare v_exp_f32. P->bf16 via cvt_pk +
// permlane32_swap (T12).
__global__ __launch_bounds__(256, 4) void attn(const u16* __restrict__ qkv,
                                               const u16* __restrict__ vT,
                                               u16* __restrict__ ctx) {
  constexpr int S = 2048, E = 1024, TE = 3072, NT = S / 64;
  // bijective id -> (qt, bh) with XCD chunking (XCD = id & 7 on 8-XCD MI355X)
  const int id = blockIdx.x;
  const int x = id & 7, j = id >> 3;
  const int bh = x * 8 + (j & 7), qt = j >> 3;  // qt 0..15
  const int b = bh >> 4, h = bh & 15;
  const int tid = threadIdx.x, w = tid >> 6, l = tid & 63;
  const int q = l & 31, hi = l >> 5;
  __shared__ char sm[2][16384];  // per buf: K tile [64][128B] | V^T tile [64][128B]

  // Q fragments (B-frag: col=l&31=q, k=(l>>5)*8+j), 4 d-blocks of 16
  const int qglob = qt * 128 + w * 32 + q;
  const u16* qp = qkv + (size_t)(b * S + qglob) * TE + h * 64 + hi * 8;
  bf16x8 qf[4];
#pragma unroll
  for (int d = 0; d < 4; ++d) qf[d] = *(const bf16x8*)(qp + d * 16);

  const int lr = l >> 3, lsl = (l & 7) ^ lr;  // pre-swizzled source slot (rule 21)
  const u16* gK = qkv + (size_t)(b * S) * TE + E + h * 64 + lsl * 8;
  const u16* gV = vT + (size_t)(bh * 64) * S + lsl * 8;

  auto stage = [&](int t, int pp) {
    char* bk = sm[pp] + w * 2048;  // wave w stages rows w*16..w*16+15 of K and V^T
#pragma unroll
    for (int i = 0; i < 2; ++i) {
      const int row = w * 16 + i * 8 + lr;
      g2l16(gK + (size_t)(t * 64 + row) * TE, bk + i * 1024);      // K rows (kv)
      g2l16(gV + (size_t)row * S + t * 64, bk + 8192 + i * 1024);  // V^T rows (d)
    }
  };

  f32x16 o0 = {}, o1 = {};
  float lsum = 0.f;

  // p = 2^x directly (scale folded into Q upstream; constant shift cancels)
  auto expsum = [&](f32x16& e, float& ls) {
    float ts[4] = {0.f, 0.f, 0.f, 0.f};
#pragma unroll
    for (int r = 0; r < 16; ++r) {
      e[r] = fexp2(e[r]);
      ts[r & 3] += e[r];
    }
    ls += (ts[0] + ts[1]) + (ts[2] + ts[3]);
  };
  // P->bf16 B-frags in-register (T12): P0 = kv sub 0..15, P1 = kv sub 16..31
  auto mkfrag = [&](const f32x16& e, bf16x8& P0, bf16x8& P1) {
    uint32_t a0 = cvtpk(e[0], e[1]), c0 = cvtpk(e[4], e[5]);
    uint32_t a1 = cvtpk(e[2], e[3]), c1 = cvtpk(e[6], e[7]);
    pswap(a0, c0); pswap(a1, c1);
    uint32_t a2 = cvtpk(e[8], e[9]), c2 = cvtpk(e[12], e[13]);
    uint32_t a3 = cvtpk(e[10], e[11]), c3 = cvtpk(e[14], e[15]);
    pswap(a2, c2); pswap(a3, c3);
    union { uint32_t u[4]; bf16x8 v; } t0, t1;
    t0.u[0] = a0; t0.u[1] = a1; t0.u[2] = c0; t0.u[3] = c1;
    t1.u[0] = a2; t1.u[1] = a3; t1.u[2] = c2; t1.u[3] = c3;
    P0 = t0.v; P1 = t1.v;
  };

  int pp = 0;
  stage(0, 0);
  __syncthreads();
  for (int t = 0; t < NT; ++t) {
    if (t + 1 < NT) stage(t + 1, pp ^ 1);
    const char* bK = sm[pp];
    const char* bV = sm[pp] + 8192;
    const int swz = (q & 7) << 4;
#pragma unroll
    for (int s = 0; s < 2; ++s) {  // 32-kv sub-pass: one live score block
      const char* kr = bK + (s * 32 + q) * 128;
      bf16x8 kf[4];
#pragma unroll
      for (int d = 0; d < 4; ++d) kf[d] = lds_ld(kr + (((d * 2 + hi) << 4) ^ swz));
      f32x16 st = {};
      __builtin_amdgcn_s_setprio(1);
#pragma unroll
      for (int d = 0; d < 4; ++d) st = mfma32(kf[d], qf[d], st);
      __builtin_amdgcn_s_setprio(0);
      // V-frags issued early: lgkm latency hides under the softmax VALU work
      const int s0 = (((s * 4 + hi) << 4) ^ swz);
      const int s1 = (((s * 4 + 2 + hi) << 4) ^ swz);
      const bf16x8 va0 = lds_ld(bV + q * 128 + s0);
      const bf16x8 va1 = lds_ld(bV + q * 128 + s1);
      const bf16x8 vb0 = lds_ld(bV + (32 + q) * 128 + s0);
      const bf16x8 vb1 = lds_ld(bV + (32 + q) * 128 + s1);
      expsum(st, lsum);
      bf16x8 p0, p1;
      mkfrag(st, p0, p1);
      __builtin_amdgcn_s_setprio(1);
      o0 = mfma32(va0, p0, o0);
      o0 = mfma32(va1, p1, o0);
      o1 = mfma32(vb0, p0, o1);
      o1 = mfma32(vb1, p1, o1);
      __builtin_amdgcn_s_setprio(0);
    }
    __syncthreads();
    pp ^= 1;
  }
  // epilogue: O^T reg r -> d = db*32 + (r&3) + 8*(r>>2) + 4*hi, row = qglob
  const float inv = 1.0f / xhalf_sum(lsum);
  u16* cp = ctx + (size_t)(b * S + qglob) * E + h * 64 + 4 * hi;
#pragma unroll
  for (int g = 0; g < 4; ++g) {
    ushort4 pk0, pk1;
    pk0.x = f2bf(o0[4 * g + 0] * inv); pk0.y = f2bf(o0[4 * g + 1] * inv);
    pk0.z = f2bf(o0[4 * g + 2] * inv); pk0.w = f2bf(o0[4 * g + 3] * inv);
    *(ushort4*)(cp + 8 * g) = pk0;
    pk1.x = f2bf(o1[4 * g + 0] * inv); pk1.y = f2bf(o1[4 * g + 1] * inv);
    pk1.z = f2bf(o1[4 * g + 2] * inv); pk1.w = f2bf(o1[4 * g + 3] * inv);
    *(ushort4*)(cp + 32 + 8 * g) = pk1;
  }
}

extern "C" void kernel_launch(void* const* d_in, const int* in_sizes, int n_in,
                              void* d_out, int out_size, void* d_ws, size_t ws_size,
                              hipStream_t stream) {
  (void)in_sizes; (void)n_in; (void)out_size;
  const float* inp   = (const float*)d_in[0];
  const float* qkv_w = (const float*)d_in[1];
  const float* qkv_b = (const float*)d_in[2];
  const float* out_w = (const float*)d_in[3];
  const float* out_b = (const float*)d_in[4];
  char* ws = (char*)d_ws;
  if (ws_size < 92274688u) return;  // need ~88 MB scratch

  u16* inp_b  = (u16*)(ws);                  // 16,777,216 B  (reused as ctx later)
  u16* qkvw_b = (u16*)(ws + 16777216);       //  6,291,456 B
  u16* outw_b = (u16*)(ws + 23068672);       //  2,097,152 B
  u16* qkvo   = (u16*)(ws + 25165824);       // 50,331,648 B  [8192, 3072] bf16 (V cols unused)
  u16* vTb    = (u16*)(ws + 75497472);       // 16,777,216 B  [B*H*64, 2048] bf16
  u16* ctx    = inp_b;

  const float cexp = 0.18033688f;  // log2(e)/sqrt(64), folded into Q columns

  hipLaunchKernelGGL(cvt_kernel, dim3(8192), dim3(256), 0, stream, inp, inp_b, 2097152);
  hipLaunchKernelGGL(cvt_kernel, dim3(3072), dim3(256), 0, stream, qkv_w, qkvw_b, 786432);
  hipLaunchKernelGGL(cvt_kernel, dim3(1024), dim3(256), 0, stream, out_w, outw_b, 262144);
  hipLaunchKernelGGL((gemm_bt<1>), dim3(64, 24), dim3(256), 0, stream,
                     inp_b, qkvw_b, qkv_b, (void*)qkvo, vTb,
                     8192, 3072, 1024, 1024, cexp, 2048);
  hipLaunchKernelGGL(attn, dim3(1024), dim3(256), 0, stream, qkvo, vTb, ctx);
  hipLaunchKernelGGL((gemm_bt<0>), dim3(64, 8), dim3(256), 0, stream,
                     ctx, outw_b, out_b, d_out, (u16*)nullptr,
                     8192, 1024, 1024, 0, 1.0f, 1 << 30);
}

// Round 14
// 172.373 us; speedup vs baseline: 4.3235x; 1.0011x over previous
//
#include <hip/hip_runtime.h>
#include <stdint.h>

typedef unsigned short u16;
typedef __bf16 bf16x8 __attribute__((ext_vector_type(8)));
typedef float f32x4 __attribute__((ext_vector_type(4)));
typedef float f32x16 __attribute__((ext_vector_type(16)));

#define DEV static __device__ __forceinline__

// f32 -> bf16 round-to-nearest-even (finite inputs only)
DEV u16 f2bf(float f) {
  uint32_t u = __float_as_uint(f);
  u += 0x7fffu + ((u >> 16) & 1u);
  return (u16)(u >> 16);
}

// async global->LDS, 16B per lane; lds dest is wave-uniform base (HW adds lane*16)
DEV void g2l16(const void* g, void* l) {
  __builtin_amdgcn_global_load_lds(
      (__attribute__((address_space(1))) void*)(g),
      (__attribute__((address_space(3))) void*)(l), 16, 0, 0);
}

DEV f32x4 mfma16(bf16x8 a, bf16x8 b, f32x4 c) {
  return __builtin_amdgcn_mfma_f32_16x16x32_bf16(a, b, c, 0, 0, 0);
}
DEV f32x16 mfma32(bf16x8 a, bf16x8 b, f32x16 c) {
  return __builtin_amdgcn_mfma_f32_32x32x16_bf16(a, b, c, 0, 0, 0);
}

DEV bf16x8 lds_ld(const char* p) { return *(const bf16x8*)p; }

// single-instruction 2^x (avoids any OCML exp2 codepath)
DEV float fexp2(float x) {
  float r;
  asm("v_exp_f32 %0, %1" : "=v"(r) : "v"(x));
  return r;
}

// pack two f32 to one u32 of 2 bf16 (lo from src0)
DEV uint32_t cvtpk(float lo, float hi) {
  uint32_t r;
  asm("v_cvt_pk_bf16_f32 %0, %1, %2" : "=v"(r) : "v"(lo), "v"(hi));
  return r;
}
// swap: a.hi-lanes <-> b.lo-lanes (T12 redistribution primitive)
DEV void pswap(uint32_t& a, uint32_t& b) {
  auto r = __builtin_amdgcn_permlane32_swap((int)a, (int)b, false, false);
  a = (uint32_t)r[0];
  b = (uint32_t)r[1];
}
DEV float xhalf_sum(float x) {
  auto r = __builtin_amdgcn_permlane32_swap(__float_as_int(x), __float_as_int(x), false, false);
  return __int_as_float(r[0]) + __int_as_float(r[1]);
}

// ---------------- f32 -> bf16 cast, 4 elems/thread ----------------
__global__ __launch_bounds__(256) void cvt_kernel(const float* __restrict__ in,
                                                  u16* __restrict__ out, int n4) {
  int i = blockIdx.x * 256 + threadIdx.x;
  if (i >= n4) return;
  float4 v = ((const float4*)in)[i];
  ushort4 o;
  o.x = f2bf(v.x); o.y = f2bf(v.y); o.z = f2bf(v.z); o.w = f2bf(v.w);
  ((ushort4*)out)[i] = o;
}

// ---------------- C[M,N] = A[M,K] * B[N,K]^T + bias (R8 known-good) ----------------
// EPI=1 (qkv gemm): cols < qcols scaled by qscale (softmax scale folded into Q);
//   tiles with bn0 >= vcol0 are the V slice, written TRANSPOSED into vT.
// EPI=0: plain f32 C output.
template<int EPI>
__global__ __launch_bounds__(256, 2) void gemm_bt(
    const u16* __restrict__ A, const u16* __restrict__ B,
    const float* __restrict__ bias, void* __restrict__ C,
    u16* __restrict__ vT,
    int M, int N, int K, int qcols, float qscale, int vcol0) {
  __shared__ char sm[2][32768];
  const int tid = threadIdx.x;
  const int w = tid >> 6, l = tid & 63;
  const int wr = w >> 1, wc = w & 1;
  const int bm0 = blockIdx.x * 128, bn0 = blockIdx.y * 128;
  const int lr = l >> 3, lsl = (l & 7) ^ lr;
  const u16* gA = A + (size_t)(bm0 + w * 32 + lr) * K + lsl * 8;
  const u16* gB = B + (size_t)(bn0 + w * 32 + lr) * K + lsl * 8;

  auto stage = [&](int t, int pp) {
    char* ba = sm[pp] + w * 32 * 128;
    char* bb = ba + 16384;
    const u16* a = gA + t * 64;
    const u16* b = gB + t * 64;
#pragma unroll
    for (int i = 0; i < 4; ++i) {
      g2l16(a + (size_t)i * 8 * K, ba + i * 8 * 128);
      g2l16(b + (size_t)i * 8 * K, bb + i * 8 * 128);
    }
  };

  f32x4 acc[4][4] = {};
  const int NT = K / 64;
  int pp = 0;
  stage(0, 0);
  __syncthreads();
  for (int t = 0; t < NT; ++t) {
    if (t + 1 < NT) stage(t + 1, pp ^ 1);
    const char* bufA = sm[pp];
    const char* bufB = bufA + 16384;
#pragma unroll
    for (int ks = 0; ks < 2; ++ks) {
      bf16x8 af[4], bfr[4];
#pragma unroll
      for (int i = 0; i < 4; ++i) {
        const int rowA = wr * 64 + i * 16 + (l & 15);
        const int colb = (ks * 64 + ((l >> 4) << 4)) ^ ((rowA & 7) << 4);
        af[i] = lds_ld(bufA + rowA * 128 + colb);
        const int rowB = wc * 64 + i * 16 + (l & 15);
        bfr[i] = lds_ld(bufB + rowB * 128 + colb);
      }
#pragma unroll
      for (int i = 0; i < 4; ++i)
#pragma unroll
        for (int j = 0; j < 4; ++j)
          acc[i][j] = mfma16(af[i], bfr[j], acc[i][j]);
    }
    __syncthreads();
    pp ^= 1;
  }
  const int cr = (l >> 4) * 4, cc = l & 15;
  if (EPI == 1 && bn0 >= vcol0) {
#pragma unroll
    for (int i = 0; i < 4; ++i) {
      const int gr = bm0 + wr * 64 + i * 16 + cr;
      const int b = gr >> 11, s = gr & 2047;
#pragma unroll
      for (int j = 0; j < 4; ++j) {
        const int gc = bn0 + wc * 64 + j * 16 + cc;
        const float bv = bias[gc];
        const int vc = gc - vcol0;
        u16* dst = vT + ((size_t)((b * 16 + (vc >> 6)) * 64 + (vc & 63))) * 2048 + s;
        ushort4 pk;
        pk.x = f2bf(acc[i][j][0] + bv);
        pk.y = f2bf(acc[i][j][1] + bv);
        pk.z = f2bf(acc[i][j][2] + bv);
        pk.w = f2bf(acc[i][j][3] + bv);
        *(ushort4*)dst = pk;
      }
    }
    return;
  }
#pragma unroll
  for (int i = 0; i < 4; ++i) {
    const int gr = bm0 + wr * 64 + i * 16 + cr;
#pragma unroll
    for (int j = 0; j < 4; ++j) {
      const int gc = bn0 + wc * 64 + j * 16 + cc;
      const float bv = bias[gc];
      const float scl = (gc < qcols) ? qscale : 1.0f;
#pragma unroll
      for (int r = 0; r < 4; ++r) {
        const float v = (acc[i][j][r] + bv) * scl;
        if (EPI == 0) ((float*)C)[(size_t)(gr + r) * N + gc] = v;
        else          ((u16*)C)[(size_t)(gr + r) * N + gc] = f2bf(v);
      }
    }
  }
}

// ---------------- flash attention: R8 structure + 8-row-group LDS padding ----------------
// 1-D grid 512, 256 thr = 4 waves x 64 q-rows (two 32-q blocks A/B), XCD-chunked bh map.
// NEW: LDS rows are grouped 8 rows/1056B (1024 data + 32 pad). A 128B row stride makes
// bank == slot (row*128/4 % 32 == 0) -> every b128 read was a structural 4-way conflict
// (32 lanes, 8 slots). Group stride 1056 shifts banks by 8*(group%4) words: the 4 lanes
// sharing a slot (q, q+8, q+16, q+24) now land on banks +{0,8,16,24} -> full 32-bank
// spread, 2 lanes/bank = the free minimum (m136). g2l16 writes (8 rows = 1KB dense)
// stay legal; data content is byte-identical to R8 -> numerics unchanged.
__global__ __launch_bounds__(256, 2) void attn(const u16* __restrict__ qkv,
                                               const u16* __restrict__ vT,
                                               u16* __restrict__ ctx) {
  constexpr int S = 2048, E = 1024, TE = 3072, NT = S / 64;
  constexpr int GS = 1056;             // 8-row group stride (1024 + 32 pad)
  constexpr int HALF = 8 * GS;         // one K or V tile: 8 groups = 8448 B
  const int id = blockIdx.x;
  const int x = id & 7, j = id >> 3;
  const int bh = x * 8 + (j & 7), qt = j >> 3;
  const int b = bh >> 4, h = bh & 15;
  const int tid = threadIdx.x, w = tid >> 6, l = tid & 63;
  const int q = l & 31, hi = l >> 5;
  __shared__ char sm[2][2 * 8 * GS];   // per buf: K tile 8448 | V^T tile 8448

  // Q fragments (B-frag: col=q, k=hi*8+j), 4 d-blocks of 16, two q-blocks
  const int qglobA = qt * 256 + w * 64 + q;
  const int qglobB = qglobA + 32;
  const u16* qpA = qkv + (size_t)(b * S + qglobA) * TE + h * 64 + hi * 8;
  const u16* qpB = qkv + (size_t)(b * S + qglobB) * TE + h * 64 + hi * 8;
  bf16x8 qfA[4], qfB[4];
#pragma unroll
  for (int d = 0; d < 4; ++d) {
    qfA[d] = *(const bf16x8*)(qpA + d * 16);
    qfB[d] = *(const bf16x8*)(qpB + d * 16);
  }

  const int lr = l >> 3, lsl = (l & 7) ^ lr;  // pre-swizzled source slot (rule 21)
  const u16* gK = qkv + (size_t)(b * S) * TE + E + h * 64 + lsl * 8;
  const u16* gV = vT + (size_t)(bh * 64) * S + lsl * 8;

  auto stage = [&](int t, int pp) {
    char* base = sm[pp];
#pragma unroll
    for (int i = 0; i < 2; ++i) {
      const int grp = w * 2 + i;                 // 8-row group index
      const int row = w * 16 + i * 8 + lr;
      g2l16(gK + (size_t)(t * 64 + row) * TE, base + grp * GS);         // K rows (kv)
      g2l16(gV + (size_t)row * S + t * 64, base + HALF + grp * GS);     // V^T rows (d)
    }
  };

  f32x16 o0A = {}, o1A = {}, o0B = {}, o1B = {};
  float lsumA = 0.f, lsumB = 0.f;

  auto expsum = [&](f32x16& e, float& ls) {
    float ts[4] = {0.f, 0.f, 0.f, 0.f};
#pragma unroll
    for (int r = 0; r < 16; ++r) {
      e[r] = fexp2(e[r]);
      ts[r & 3] += e[r];
    }
    ls += (ts[0] + ts[1]) + (ts[2] + ts[3]);
  };
  auto mkfrag = [&](const f32x16& e, bf16x8& P0, bf16x8& P1) {
    uint32_t a0 = cvtpk(e[0], e[1]), c0 = cvtpk(e[4], e[5]);
    uint32_t a1 = cvtpk(e[2], e[3]), c1 = cvtpk(e[6], e[7]);
    pswap(a0, c0); pswap(a1, c1);
    uint32_t a2 = cvtpk(e[8], e[9]), c2 = cvtpk(e[12], e[13]);
    uint32_t a3 = cvtpk(e[10], e[11]), c3 = cvtpk(e[14], e[15]);
    pswap(a2, c2); pswap(a3, c3);
    union { uint32_t u[4]; bf16x8 v; } t0, t1;
    t0.u[0] = a0; t0.u[1] = a1; t0.u[2] = c0; t0.u[3] = c1;
    t1.u[0] = a2; t1.u[1] = a3; t1.u[2] = c2; t1.u[3] = c3;
    P0 = t0.v; P1 = t1.v;
  };

  int pp = 0;
  stage(0, 0);
  __syncthreads();
  for (int t = 0; t < NT; ++t) {
    if (t + 1 < NT) stage(t + 1, pp ^ 1);
    const char* bK = sm[pp];
    const char* bV = sm[pp] + HALF;
    const int swz = (q & 7) << 4;
    // padded-row addressing: row r -> (r>>3)*GS + (r&7)*128
    const char* vr0 = bV + (q >> 3) * GS + (q & 7) * 128;          // V^T row q
    const char* vr1 = bV + (4 + (q >> 3)) * GS + (q & 7) * 128;    // V^T row 32+q
#pragma unroll
    for (int s = 0; s < 2; ++s) {  // 32-kv sub-pass
      const char* kr = bK + (s * 4 + (q >> 3)) * GS + (q & 7) * 128;  // K row s*32+q
      bf16x8 kf[4];
#pragma unroll
      for (int d = 0; d < 4; ++d) kf[d] = lds_ld(kr + (((d * 2 + hi) << 4) ^ swz));
      f32x16 stA = {}, stB = {};
      __builtin_amdgcn_s_setprio(1);
#pragma unroll
      for (int d = 0; d < 4; ++d) {  // interleaved A/B chains: 2x MFMA ILP
        stA = mfma32(kf[d], qfA[d], stA);
        stB = mfma32(kf[d], qfB[d], stB);
      }
      __builtin_amdgcn_s_setprio(0);
      // V-frags issued early: lgkm latency hides under the softmax VALU work
      const int s0 = (((s * 4 + hi) << 4) ^ swz);
      const int s1 = (((s * 4 + 2 + hi) << 4) ^ swz);
      const bf16x8 va0 = lds_ld(vr0 + s0);
      const bf16x8 va1 = lds_ld(vr0 + s1);
      const bf16x8 vb0 = lds_ld(vr1 + s0);
      const bf16x8 vb1 = lds_ld(vr1 + s1);
      expsum(stA, lsumA);
      expsum(stB, lsumB);
      bf16x8 pA0, pA1, pB0, pB1;
      mkfrag(stA, pA0, pA1);
      mkfrag(stB, pB0, pB1);
      __builtin_amdgcn_s_setprio(1);
      o0A = mfma32(va0, pA0, o0A); o0B = mfma32(va0, pB0, o0B);
      o0A = mfma32(va1, pA1, o0A); o0B = mfma32(va1, pB1, o0B);
      o1A = mfma32(vb0, pA0, o1A); o1B = mfma32(vb0, pB0, o1B);
      o1A = mfma32(vb1, pA1, o1A); o1B = mfma32(vb1, pB1, o1B);
      __builtin_amdgcn_s_setprio(0);
    }
    __syncthreads();
    pp ^= 1;
  }
  // epilogue: O^T reg r -> d = db*32 + (r&3) + 8*(r>>2) + 4*hi, row = qglob
  auto writeo = [&](const f32x16& e0, const f32x16& e1, float ls, int qg) {
    const float inv = 1.0f / xhalf_sum(ls);
    u16* cp = ctx + (size_t)(b * S + qg) * E + h * 64 + 4 * hi;
#pragma unroll
    for (int g = 0; g < 4; ++g) {
      ushort4 pk0, pk1;
      pk0.x = f2bf(e0[4 * g + 0] * inv); pk0.y = f2bf(e0[4 * g + 1] * inv);
      pk0.z = f2bf(e0[4 * g + 2] * inv); pk0.w = f2bf(e0[4 * g + 3] * inv);
      *(ushort4*)(cp + 8 * g) = pk0;
      pk1.x = f2bf(e1[4 * g + 0] * inv); pk1.y = f2bf(e1[4 * g + 1] * inv);
      pk1.z = f2bf(e1[4 * g + 2] * inv); pk1.w = f2bf(e1[4 * g + 3] * inv);
      *(ushort4*)(cp + 32 + 8 * g) = pk1;
    }
  };
  writeo(o0A, o1A, lsumA, qglobA);
  writeo(o0B, o1B, lsumB, qglobB);
}

extern "C" void kernel_launch(void* const* d_in, const int* in_sizes, int n_in,
                              void* d_out, int out_size, void* d_ws, size_t ws_size,
                              hipStream_t stream) {
  (void)in_sizes; (void)n_in; (void)out_size;
  const float* inp   = (const float*)d_in[0];
  const float* qkv_w = (const float*)d_in[1];
  const float* qkv_b = (const float*)d_in[2];
  const float* out_w = (const float*)d_in[3];
  const float* out_b = (const float*)d_in[4];
  char* ws = (char*)d_ws;
  if (ws_size < 92274688u) return;  // need ~88 MB scratch

  u16* inp_b  = (u16*)(ws);                  // 16,777,216 B  (reused as ctx later)
  u16* qkvw_b = (u16*)(ws + 16777216);       //  6,291,456 B
  u16* outw_b = (u16*)(ws + 23068672);       //  2,097,152 B
  u16* qkvo   = (u16*)(ws + 25165824);       // 50,331,648 B  [8192, 3072] bf16 (V cols unused)
  u16* vTb    = (u16*)(ws + 75497472);       // 16,777,216 B  [B*H*64, 2048] bf16
  u16* ctx    = inp_b;

  const float cexp = 0.18033688f;  // log2(e)/sqrt(64), folded into Q columns

  hipLaunchKernelGGL(cvt_kernel, dim3(8192), dim3(256), 0, stream, inp, inp_b, 2097152);
  hipLaunchKernelGGL(cvt_kernel, dim3(3072), dim3(256), 0, stream, qkv_w, qkvw_b, 786432);
  hipLaunchKernelGGL(cvt_kernel, dim3(1024), dim3(256), 0, stream, out_w, outw_b, 262144);
  hipLaunchKernelGGL((gemm_bt<1>), dim3(64, 24), dim3(256), 0, stream,
                     inp_b, qkvw_b, qkv_b, (void*)qkvo, vTb,
                     8192, 3072, 1024, 1024, cexp, 2048);
  hipLaunchKernelGGL(attn, dim3(512), dim3(256), 0, stream, qkvo, vTb, ctx);
  hipLaunchKernelGGL((gemm_bt<0>), dim3(64, 8), dim3(256), 0, stream,
                     ctx, outw_b, out_b, d_out, (u16*)nullptr,
                     8192, 1024, 1024, 0, 1.0f, 1 << 30);
}

// Round 15
// 168.595 us; speedup vs baseline: 4.4204x; 1.0224x over previous
//
#include <hip/hip_runtime.h>
#include <stdint.h>

typedef unsigned short u16;
typedef __bf16 bf16x8 __attribute__((ext_vector_type(8)));
typedef float f32x4 __attribute__((ext_vector_type(4)));
typedef float f32x16 __attribute__((ext_vector_type(16)));

#define DEV static __device__ __forceinline__

// f32 -> bf16 round-to-nearest-even (finite inputs only)
DEV u16 f2bf(float f) {
  uint32_t u = __float_as_uint(f);
  u += 0x7fffu + ((u >> 16) & 1u);
  return (u16)(u >> 16);
}

// async global->LDS, 16B per lane; lds dest is wave-uniform base (HW adds lane*16)
DEV void g2l16(const void* g, void* l) {
  __builtin_amdgcn_global_load_lds(
      (__attribute__((address_space(1))) void*)(g),
      (__attribute__((address_space(3))) void*)(l), 16, 0, 0);
}

DEV f32x4 mfma16(bf16x8 a, bf16x8 b, f32x4 c) {
  return __builtin_amdgcn_mfma_f32_16x16x32_bf16(a, b, c, 0, 0, 0);
}
DEV f32x16 mfma32(bf16x8 a, bf16x8 b, f32x16 c) {
  return __builtin_amdgcn_mfma_f32_32x32x16_bf16(a, b, c, 0, 0, 0);
}

DEV bf16x8 lds_ld(const char* p) { return *(const bf16x8*)p; }

// single-instruction 2^x (avoids any OCML exp2 codepath)
DEV float fexp2(float x) {
  float r;
  asm("v_exp_f32 %0, %1" : "=v"(r) : "v"(x));
  return r;
}

// pack two f32 to one u32 of 2 bf16 (lo from src0)
DEV uint32_t cvtpk(float lo, float hi) {
  uint32_t r;
  asm("v_cvt_pk_bf16_f32 %0, %1, %2" : "=v"(r) : "v"(lo), "v"(hi));
  return r;
}
// swap: a.hi-lanes <-> b.lo-lanes (T12 redistribution primitive)
DEV void pswap(uint32_t& a, uint32_t& b) {
  auto r = __builtin_amdgcn_permlane32_swap((int)a, (int)b, false, false);
  a = (uint32_t)r[0];
  b = (uint32_t)r[1];
}
DEV float xhalf_sum(float x) {
  auto r = __builtin_amdgcn_permlane32_swap(__float_as_int(x), __float_as_int(x), false, false);
  return __int_as_float(r[0]) + __int_as_float(r[1]);
}

// ---------------- fused f32 -> bf16 cast for all three inputs ----------------
// One launch replaces three (saves inter-kernel gaps); ranges are block-aligned
// (n0, n1 multiples of 256) so the range branch is block-uniform.
__global__ __launch_bounds__(256) void cvt3_kernel(
    const float* __restrict__ s0, u16* __restrict__ d0, int n0,
    const float* __restrict__ s1, u16* __restrict__ d1, int n1,
    const float* __restrict__ s2, u16* __restrict__ d2, int n2) {
  int i = blockIdx.x * 256 + threadIdx.x;
  const float* s;
  u16* d;
  if (i < n0) {
    s = s0; d = d0;
  } else if (i < n0 + n1) {
    i -= n0; s = s1; d = d1;
  } else {
    i -= n0 + n1;
    if (i >= n2) return;
    s = s2; d = d2;
  }
  float4 v = ((const float4*)s)[i];
  ushort4 o;
  o.x = f2bf(v.x); o.y = f2bf(v.y); o.z = f2bf(v.z); o.w = f2bf(v.w);
  ((ushort4*)d)[i] = o;
}

// ---------------- C[M,N] = A[M,K] * B[N,K]^T + bias (proven best) ----------------
// 128x128 tile, BK=64, 4 waves (2x2), gload_lds staging, XOR-swizzled LDS,
// 2-phase double buffer (stage-next -> compute -> sync), 2 blocks/CU.
// EPI=1 (qkv gemm): cols < qcols scaled by qscale (softmax scale folded into Q);
//   tiles with bn0 >= vcol0 are the V slice, written TRANSPOSED into vT straight
//   from the f32 accumulator (separate transpose kernel eliminated).
// EPI=0: plain f32 C output.
template<int EPI>
__global__ __launch_bounds__(256, 2) void gemm_bt(
    const u16* __restrict__ A, const u16* __restrict__ B,
    const float* __restrict__ bias, void* __restrict__ C,
    u16* __restrict__ vT,
    int M, int N, int K, int qcols, float qscale, int vcol0) {
  __shared__ char sm[2][32768];
  const int tid = threadIdx.x;
  const int w = tid >> 6, l = tid & 63;
  const int wr = w >> 1, wc = w & 1;
  const int bm0 = blockIdx.x * 128, bn0 = blockIdx.y * 128;
  const int lr = l >> 3, lsl = (l & 7) ^ lr;
  const u16* gA = A + (size_t)(bm0 + w * 32 + lr) * K + lsl * 8;
  const u16* gB = B + (size_t)(bn0 + w * 32 + lr) * K + lsl * 8;

  auto stage = [&](int t, int pp) {
    char* ba = sm[pp] + w * 32 * 128;
    char* bb = ba + 16384;
    const u16* a = gA + t * 64;
    const u16* b = gB + t * 64;
#pragma unroll
    for (int i = 0; i < 4; ++i) {
      g2l16(a + (size_t)i * 8 * K, ba + i * 8 * 128);
      g2l16(b + (size_t)i * 8 * K, bb + i * 8 * 128);
    }
  };

  f32x4 acc[4][4] = {};
  const int NT = K / 64;
  int pp = 0;
  stage(0, 0);
  __syncthreads();
  for (int t = 0; t < NT; ++t) {
    if (t + 1 < NT) stage(t + 1, pp ^ 1);
    const char* bufA = sm[pp];
    const char* bufB = bufA + 16384;
#pragma unroll
    for (int ks = 0; ks < 2; ++ks) {
      bf16x8 af[4], bfr[4];
#pragma unroll
      for (int i = 0; i < 4; ++i) {
        const int rowA = wr * 64 + i * 16 + (l & 15);
        const int colb = (ks * 64 + ((l >> 4) << 4)) ^ ((rowA & 7) << 4);
        af[i] = lds_ld(bufA + rowA * 128 + colb);
        const int rowB = wc * 64 + i * 16 + (l & 15);
        bfr[i] = lds_ld(bufB + rowB * 128 + colb);
      }
#pragma unroll
      for (int i = 0; i < 4; ++i)
#pragma unroll
        for (int j = 0; j < 4; ++j)
          acc[i][j] = mfma16(af[i], bfr[j], acc[i][j]);
    }
    __syncthreads();
    pp ^= 1;
  }
  const int cr = (l >> 4) * 4, cc = l & 15;
  if (EPI == 1 && bn0 >= vcol0) {
    // V-slice tile: transposed store straight from accumulator.
#pragma unroll
    for (int i = 0; i < 4; ++i) {
      const int gr = bm0 + wr * 64 + i * 16 + cr;
      const int b = gr >> 11, s = gr & 2047;
#pragma unroll
      for (int j = 0; j < 4; ++j) {
        const int gc = bn0 + wc * 64 + j * 16 + cc;
        const float bv = bias[gc];
        const int vc = gc - vcol0;
        u16* dst = vT + ((size_t)((b * 16 + (vc >> 6)) * 64 + (vc & 63))) * 2048 + s;
        ushort4 pk;
        pk.x = f2bf(acc[i][j][0] + bv);
        pk.y = f2bf(acc[i][j][1] + bv);
        pk.z = f2bf(acc[i][j][2] + bv);
        pk.w = f2bf(acc[i][j][3] + bv);
        *(ushort4*)dst = pk;
      }
    }
    return;
  }
#pragma unroll
  for (int i = 0; i < 4; ++i) {
    const int gr = bm0 + wr * 64 + i * 16 + cr;
#pragma unroll
    for (int j = 0; j < 4; ++j) {
      const int gc = bn0 + wc * 64 + j * 16 + cc;
      const float bv = bias[gc];
      const float scl = (gc < qcols) ? qscale : 1.0f;
#pragma unroll
      for (int r = 0; r < 4; ++r) {
        const float v = (acc[i][j][r] + bv) * scl;
        if (EPI == 0) ((float*)C)[(size_t)(gr + r) * N + gc] = v;
        else          ((u16*)C)[(size_t)(gr + r) * N + gc] = f2bf(v);
      }
    }
  }
}

// ---------------- flash attention (proven best: R8 structure) ----------------
// 1-D grid 512, 256 thr = 4 waves x 64 q-rows (two 32-q blocks A/B).
// XCD-chunked bh map: XCD x owns bh in [8x,8x+8) -> each XCD's L2 holds its
// 8 bh's K+V (4MB): staging hits L2, FETCH -74% (R7). Swapped-QK^T 32x32 with
// in-register softmax; fixed-max shift cancels in the normalize -> exp is a
// bare v_exp_f32 (scale folded into Q by gemm1). P->bf16 via cvt_pk +
// permlane32_swap (T12). Measured 83 us; invariant to occupancy (R12), LDS
// traffic (R5), and bank conflicts (R14) -> mixed-issue bound for this design.
__global__ __launch_bounds__(256, 2) void attn(const u16* __restrict__ qkv,
                                               const u16* __restrict__ vT,
                                               u16* __restrict__ ctx) {
  constexpr int S = 2048, E = 1024, TE = 3072, NT = S / 64;
  const int id = blockIdx.x;
  const int x = id & 7, j = id >> 3;
  const int bh = x * 8 + (j & 7), qt = j >> 3;
  const int b = bh >> 4, h = bh & 15;
  const int tid = threadIdx.x, w = tid >> 6, l = tid & 63;
  const int q = l & 31, hi = l >> 5;
  __shared__ char sm[2][16384];  // per buf: K tile [64][128B] | V^T tile [64][128B]

  const int qglobA = qt * 256 + w * 64 + q;
  const int qglobB = qglobA + 32;
  const u16* qpA = qkv + (size_t)(b * S + qglobA) * TE + h * 64 + hi * 8;
  const u16* qpB = qkv + (size_t)(b * S + qglobB) * TE + h * 64 + hi * 8;
  bf16x8 qfA[4], qfB[4];
#pragma unroll
  for (int d = 0; d < 4; ++d) {
    qfA[d] = *(const bf16x8*)(qpA + d * 16);
    qfB[d] = *(const bf16x8*)(qpB + d * 16);
  }

  const int lr = l >> 3, lsl = (l & 7) ^ lr;  // pre-swizzled source slot (rule 21)
  const u16* gK = qkv + (size_t)(b * S) * TE + E + h * 64 + lsl * 8;
  const u16* gV = vT + (size_t)(bh * 64) * S + lsl * 8;

  auto stage = [&](int t, int pp) {
    char* bk = sm[pp] + w * 2048;  // wave w stages rows w*16..w*16+15 of K and V^T
#pragma unroll
    for (int i = 0; i < 2; ++i) {
      const int row = w * 16 + i * 8 + lr;
      g2l16(gK + (size_t)(t * 64 + row) * TE, bk + i * 1024);      // K rows (kv)
      g2l16(gV + (size_t)row * S + t * 64, bk + 8192 + i * 1024);  // V^T rows (d)
    }
  };

  f32x16 o0A = {}, o1A = {}, o0B = {}, o1B = {};
  float lsumA = 0.f, lsumB = 0.f;

  auto expsum = [&](f32x16& e, float& ls) {
    float ts[4] = {0.f, 0.f, 0.f, 0.f};
#pragma unroll
    for (int r = 0; r < 16; ++r) {
      e[r] = fexp2(e[r]);
      ts[r & 3] += e[r];
    }
    ls += (ts[0] + ts[1]) + (ts[2] + ts[3]);
  };
  auto mkfrag = [&](const f32x16& e, bf16x8& P0, bf16x8& P1) {
    uint32_t a0 = cvtpk(e[0], e[1]), c0 = cvtpk(e[4], e[5]);
    uint32_t a1 = cvtpk(e[2], e[3]), c1 = cvtpk(e[6], e[7]);
    pswap(a0, c0); pswap(a1, c1);
    uint32_t a2 = cvtpk(e[8], e[9]), c2 = cvtpk(e[12], e[13]);
    uint32_t a3 = cvtpk(e[10], e[11]), c3 = cvtpk(e[14], e[15]);
    pswap(a2, c2); pswap(a3, c3);
    union { uint32_t u[4]; bf16x8 v; } t0, t1;
    t0.u[0] = a0; t0.u[1] = a1; t0.u[2] = c0; t0.u[3] = c1;
    t1.u[0] = a2; t1.u[1] = a3; t1.u[2] = c2; t1.u[3] = c3;
    P0 = t0.v; P1 = t1.v;
  };

  int pp = 0;
  stage(0, 0);
  __syncthreads();
  for (int t = 0; t < NT; ++t) {
    if (t + 1 < NT) stage(t + 1, pp ^ 1);
    const char* bK = sm[pp];
    const char* bV = sm[pp] + 8192;
    const int swz = (q & 7) << 4;
#pragma unroll
    for (int s = 0; s < 2; ++s) {  // 32-kv sub-pass
      const char* kr = bK + (s * 32 + q) * 128;
      bf16x8 kf[4];
#pragma unroll
      for (int d = 0; d < 4; ++d) kf[d] = lds_ld(kr + (((d * 2 + hi) << 4) ^ swz));
      f32x16 stA = {}, stB = {};
      __builtin_amdgcn_s_setprio(1);
#pragma unroll
      for (int d = 0; d < 4; ++d) {  // interleaved A/B chains: 2x MFMA ILP
        stA = mfma32(kf[d], qfA[d], stA);
        stB = mfma32(kf[d], qfB[d], stB);
      }
      __builtin_amdgcn_s_setprio(0);
      // V-frags issued early: lgkm latency hides under the softmax VALU work
      const int s0 = (((s * 4 + hi) << 4) ^ swz);
      const int s1 = (((s * 4 + 2 + hi) << 4) ^ swz);
      const bf16x8 va0 = lds_ld(bV + q * 128 + s0);
      const bf16x8 va1 = lds_ld(bV + q * 128 + s1);
      const bf16x8 vb0 = lds_ld(bV + (32 + q) * 128 + s0);
      const bf16x8 vb1 = lds_ld(bV + (32 + q) * 128 + s1);
      expsum(stA, lsumA);
      expsum(stB, lsumB);
      bf16x8 pA0, pA1, pB0, pB1;
      mkfrag(stA, pA0, pA1);
      mkfrag(stB, pB0, pB1);
      __builtin_amdgcn_s_setprio(1);
      o0A = mfma32(va0, pA0, o0A); o0B = mfma32(va0, pB0, o0B);
      o0A = mfma32(va1, pA1, o0A); o0B = mfma32(va1, pB1, o0B);
      o1A = mfma32(vb0, pA0, o1A); o1B = mfma32(vb0, pB0, o1B);
      o1A = mfma32(vb1, pA1, o1A); o1B = mfma32(vb1, pB1, o1B);
      __builtin_amdgcn_s_setprio(0);
    }
    __syncthreads();
    pp ^= 1;
  }
  // epilogue: O^T reg r -> d = db*32 + (r&3) + 8*(r>>2) + 4*hi, row = qglob
  auto writeo = [&](const f32x16& e0, const f32x16& e1, float ls, int qg) {
    const float inv = 1.0f / xhalf_sum(ls);
    u16* cp = ctx + (size_t)(b * S + qg) * E + h * 64 + 4 * hi;
#pragma unroll
    for (int g = 0; g < 4; ++g) {
      ushort4 pk0, pk1;
      pk0.x = f2bf(e0[4 * g + 0] * inv); pk0.y = f2bf(e0[4 * g + 1] * inv);
      pk0.z = f2bf(e0[4 * g + 2] * inv); pk0.w = f2bf(e0[4 * g + 3] * inv);
      *(ushort4*)(cp + 8 * g) = pk0;
      pk1.x = f2bf(e1[4 * g + 0] * inv); pk1.y = f2bf(e1[4 * g + 1] * inv);
      pk1.z = f2bf(e1[4 * g + 2] * inv); pk1.w = f2bf(e1[4 * g + 3] * inv);
      *(ushort4*)(cp + 32 + 8 * g) = pk1;
    }
  };
  writeo(o0A, o1A, lsumA, qglobA);
  writeo(o0B, o1B, lsumB, qglobB);
}

extern "C" void kernel_launch(void* const* d_in, const int* in_sizes, int n_in,
                              void* d_out, int out_size, void* d_ws, size_t ws_size,
                              hipStream_t stream) {
  (void)in_sizes; (void)n_in; (void)out_size;
  const float* inp   = (const float*)d_in[0];
  const float* qkv_w = (const float*)d_in[1];
  const float* qkv_b = (const float*)d_in[2];
  const float* out_w = (const float*)d_in[3];
  const float* out_b = (const float*)d_in[4];
  char* ws = (char*)d_ws;
  if (ws_size < 92274688u) return;  // need ~88 MB scratch

  u16* inp_b  = (u16*)(ws);                  // 16,777,216 B  (reused as ctx later)
  u16* qkvw_b = (u16*)(ws + 16777216);       //  6,291,456 B
  u16* outw_b = (u16*)(ws + 23068672);       //  2,097,152 B
  u16* qkvo   = (u16*)(ws + 25165824);       // 50,331,648 B  [8192, 3072] bf16 (V cols unused)
  u16* vTb    = (u16*)(ws + 75497472);       // 16,777,216 B  [B*H*64, 2048] bf16
  u16* ctx    = inp_b;

  const float cexp = 0.18033688f;  // log2(e)/sqrt(64), folded into Q columns

  // fused casts: 2097152 + 786432 + 262144 float4s = 12288 blocks
  hipLaunchKernelGGL(cvt3_kernel, dim3(12288), dim3(256), 0, stream,
                     inp, inp_b, 2097152,
                     qkv_w, qkvw_b, 786432,
                     out_w, outw_b, 262144);
  hipLaunchKernelGGL((gemm_bt<1>), dim3(64, 24), dim3(256), 0, stream,
                     inp_b, qkvw_b, qkv_b, (void*)qkvo, vTb,
                     8192, 3072, 1024, 1024, cexp, 2048);
  hipLaunchKernelGGL(attn, dim3(512), dim3(256), 0, stream, qkvo, vTb, ctx);
  hipLaunchKernelGGL((gemm_bt<0>), dim3(64, 8), dim3(256), 0, stream,
                     ctx, outw_b, out_b, d_out, (u16*)nullptr,
                     8192, 1024, 1024, 0, 1.0f, 1 << 30);
}